// Round 1
// baseline (1412.075 us; speedup 1.0000x reference)
//
#include <hip/hip_runtime.h>
#include <hip/hip_bf16.h>

// Problem constants (match reference setup_inputs)
constexpr int B_   = 2048;
constexpr int L_   = 200;
constexpr int C_   = 100;
constexpr int DID_ = 64;
constexpr int DTXT_= 128;
constexpr int DCTX_= 128;
constexpr int KWIN = 5;
constexpr int V_   = 2000;
constexpr int DIN_ = DID_ + DTXT_;   // 192
constexpr int HID_ = 128;

__device__ __forceinline__ float dot4(float4 a, float4 b) {
  return a.x*b.x + a.y*b.y + a.z*b.z + a.w*b.w;
}

// ---------------------------------------------------------------------------
// K1: per-batch GRU over the K=5 window + precompute of candidate-independent
// scorer terms u_t, u_i and mixture weights alpha.
//   u_t[b,j] = bt1[j] + Wt1[j,0:128]@last_text[b] + Wt1[j,256:384]@h[b]
//   u_i[b,j] = bi1[j] + Wi1[j,0:64]@last_id[b]    + Wi1[j,128:256]@h[b]
// 8 batches per block, 512 threads = (j in 0..127) x (grp in 0..3, 2 batches).
// ---------------------------------------------------------------------------
__global__ __launch_bounds__(512) void k1_gru(
    const int*   __restrict__ lengths,
    const float* __restrict__ seq_id,
    const float* __restrict__ seq_text,
    const float* __restrict__ W_ih, const float* __restrict__ W_hh,
    const float* __restrict__ b_ih, const float* __restrict__ b_hh,
    const float* __restrict__ Wt1,  const float* __restrict__ bt1,
    const float* __restrict__ Wi1,  const float* __restrict__ bi1,
    const float* __restrict__ Wa1,  const float* __restrict__ ba1,
    const float* __restrict__ Wa2,  const float* __restrict__ ba2,
    float* __restrict__ u_t, float* __restrict__ u_i,
    float* __restrict__ alp)
{
  constexpr int TB = 8;
  __shared__ float xk[TB][KWIN][DIN_];   // 30720 B
  __shared__ float hbuf[2][TB][DCTX_];   //  8192 B
  __shared__ float ltext[TB][DTXT_];     //  4096 B
  __shared__ float lid[TB][DID_];        //  2048 B
  __shared__ float a1s[TB][64];          //  2048 B
  __shared__ int   s_start[TB], s_last[TB];

  const int tid = threadIdx.x;
  const int b0  = blockIdx.x * TB;

  if (tid < TB) {
    int len = lengths[b0 + tid];
    s_start[tid] = len - KWIN;
    s_last[tid]  = len - 1;
  }
  __syncthreads();

  // stage the GRU window: xk[b][t][:] = [id_emb(64) | text_emb(128)]
  for (int idx = tid; idx < TB*KWIN*DIN_; idx += 512) {
    int bb = idx / (KWIN*DIN_);
    int r  = idx % (KWIN*DIN_);
    int t  = r / DIN_;
    int k  = r % DIN_;
    size_t gb  = (size_t)(b0 + bb);
    int   pos = s_start[bb] + t;
    xk[bb][t][k] = (k < DID_)
        ? seq_id[(gb*L_ + pos)*DID_ + k]
        : seq_text[(gb*L_ + pos)*DTXT_ + (k - DID_)];
  }
  for (int idx = tid; idx < TB*DTXT_; idx += 512) {
    int bb = idx / DTXT_, k = idx % DTXT_;
    size_t gb = (size_t)(b0 + bb);
    ltext[bb][k] = seq_text[(gb*L_ + s_last[bb])*DTXT_ + k];
  }
  for (int idx = tid; idx < TB*DID_; idx += 512) {
    int bb = idx / DID_, k = idx % DID_;
    size_t gb = (size_t)(b0 + bb);
    lid[bb][k] = seq_id[(gb*L_ + s_last[bb])*DID_ + k];
  }
  for (int idx = tid; idx < TB*DCTX_; idx += 512)
    ((float*)hbuf[0])[idx] = 0.f;
  __syncthreads();

  const int j   = tid & 127;   // hidden unit
  const int grp = tid >> 7;    // 0..3, owns batches grp*2, grp*2+1
  int cur = 0;

  const float4* wi_r = (const float4*)W_ih + (size_t)j*48;
  const float4* wi_z = (const float4*)W_ih + (size_t)(128+j)*48;
  const float4* wi_n = (const float4*)W_ih + (size_t)(256+j)*48;
  const float4* wh_r = (const float4*)W_hh + (size_t)j*32;
  const float4* wh_z = (const float4*)W_hh + (size_t)(128+j)*32;
  const float4* wh_n = (const float4*)W_hh + (size_t)(256+j)*32;
  const float bir = b_ih[j], biz = b_ih[128+j], bin_ = b_ih[256+j];
  const float bhr = b_hh[j], bhz = b_hh[128+j], bhn  = b_hh[256+j];

  for (int t = 0; t < KWIN; ++t) {
    float air[2], aiz[2], ain[2], ahr[2], ahz[2], ahn[2];
    #pragma unroll
    for (int e = 0; e < 2; ++e) {
      air[e]=bir; aiz[e]=biz; ain[e]=bin_; ahr[e]=bhr; ahz[e]=bhz; ahn[e]=bhn;
    }
    #pragma unroll 4
    for (int k4 = 0; k4 < DIN_/4; ++k4) {
      float4 wr = wi_r[k4], wz = wi_z[k4], wn = wi_n[k4];
      #pragma unroll
      for (int e = 0; e < 2; ++e) {
        float4 x = *(const float4*)&xk[grp*2+e][t][k4*4];   // LDS broadcast
        air[e] += dot4(wr,x); aiz[e] += dot4(wz,x); ain[e] += dot4(wn,x);
      }
    }
    #pragma unroll 4
    for (int k4 = 0; k4 < DCTX_/4; ++k4) {
      float4 wr = wh_r[k4], wz = wh_z[k4], wn = wh_n[k4];
      #pragma unroll
      for (int e = 0; e < 2; ++e) {
        float4 x = *(const float4*)&hbuf[cur][grp*2+e][k4*4];
        ahr[e] += dot4(wr,x); ahz[e] += dot4(wz,x); ahn[e] += dot4(wn,x);
      }
    }
    #pragma unroll
    for (int e = 0; e < 2; ++e) {
      int bb = grp*2+e;
      float r  = 1.f/(1.f + __expf(-(air[e]+ahr[e])));
      float zg = 1.f/(1.f + __expf(-(aiz[e]+ahz[e])));
      float n  = tanhf(ain[e] + r*ahn[e]);
      hbuf[1-cur][bb][j] = (1.f - zg)*n + zg*hbuf[cur][bb][j];
    }
    __syncthreads();
    cur ^= 1;
  }
  // final hidden state is hbuf[cur]

  // u_t
  {
    const float4* wsrc = (const float4*)Wt1 + (size_t)j*96;       // cols 0:128
    const float4* whid = wsrc + 64;                               // cols 256:384
    float a0 = bt1[j], a1 = a0;
    #pragma unroll 4
    for (int k4 = 0; k4 < 32; ++k4) {
      float4 w = wsrc[k4];
      a0 += dot4(w, *(const float4*)&ltext[grp*2+0][k4*4]);
      a1 += dot4(w, *(const float4*)&ltext[grp*2+1][k4*4]);
    }
    #pragma unroll 4
    for (int k4 = 0; k4 < 32; ++k4) {
      float4 w = whid[k4];
      a0 += dot4(w, *(const float4*)&hbuf[cur][grp*2+0][k4*4]);
      a1 += dot4(w, *(const float4*)&hbuf[cur][grp*2+1][k4*4]);
    }
    u_t[((size_t)b0 + grp*2+0)*HID_ + j] = a0;
    u_t[((size_t)b0 + grp*2+1)*HID_ + j] = a1;
  }
  // u_i
  {
    const float4* wsrc = (const float4*)Wi1 + (size_t)j*64;       // cols 0:64
    const float4* whid = wsrc + 32;                               // cols 128:256
    float a0 = bi1[j], a1 = a0;
    #pragma unroll 4
    for (int k4 = 0; k4 < 16; ++k4) {
      float4 w = wsrc[k4];
      a0 += dot4(w, *(const float4*)&lid[grp*2+0][k4*4]);
      a1 += dot4(w, *(const float4*)&lid[grp*2+1][k4*4]);
    }
    #pragma unroll 4
    for (int k4 = 0; k4 < 32; ++k4) {
      float4 w = whid[k4];
      a0 += dot4(w, *(const float4*)&hbuf[cur][grp*2+0][k4*4]);
      a1 += dot4(w, *(const float4*)&hbuf[cur][grp*2+1][k4*4]);
    }
    u_i[((size_t)b0 + grp*2+0)*HID_ + j] = a0;
    u_i[((size_t)b0 + grp*2+1)*HID_ + j] = a1;
  }
  // alpha hidden layer
  if (j < 64) {
    const float4* wa = (const float4*)Wa1 + (size_t)j*32;
    float a0 = ba1[j], a1 = a0;
    #pragma unroll 4
    for (int k4 = 0; k4 < 32; ++k4) {
      float4 w = wa[k4];
      a0 += dot4(w, *(const float4*)&hbuf[cur][grp*2+0][k4*4]);
      a1 += dot4(w, *(const float4*)&hbuf[cur][grp*2+1][k4*4]);
    }
    a1s[grp*2+0][j] = fmaxf(a0, 0.f);
    a1s[grp*2+1][j] = fmaxf(a1, 0.f);
  }
  __syncthreads();
  if (tid < TB) {
    int bb = tid;
    float lg0 = ba2[0], lg1 = ba2[1], lg2 = ba2[2];
    for (int k = 0; k < 64; ++k) {
      float a = a1s[bb][k];
      lg0 += Wa2[k]*a; lg1 += Wa2[64+k]*a; lg2 += Wa2[128+k]*a;
    }
    float m  = fmaxf(lg0, fmaxf(lg1, lg2));
    float e0 = __expf(lg0-m), e1 = __expf(lg1-m), e2 = __expf(lg2-m);
    float inv = 1.f/(e0+e1+e2);
    alp[((size_t)b0+bb)*3+0] = e0*inv;
    alp[((size_t)b0+bb)*3+1] = e1*inv;
    alp[((size_t)b0+bb)*3+2] = e2*inv;
  }
}

// ---------------------------------------------------------------------------
// K2: per-batch candidate scoring + 3 softmaxes + mixture + renorm.
// One block per batch, 256 threads = (jq 0..31: 4 hidden units) x (cg 0..7: 4 cands).
// E_t/E_i staged in LDS (broadcast reads), W streamed from L2.
// ---------------------------------------------------------------------------
__global__ __launch_bounds__(256) void k2_score(
    const int*   __restrict__ seq_items,
    const int*   __restrict__ lengths,
    const int*   __restrict__ cand_ids,
    const float* __restrict__ cand_id_emb,
    const float* __restrict__ cand_text_emb,
    const float* __restrict__ co_table,
    const float* __restrict__ Wt1, const float* __restrict__ Wt2,
    const float* __restrict__ Wi1, const float* __restrict__ Wi2,
    const float* __restrict__ u_t, const float* __restrict__ u_i,
    const float* __restrict__ alp,
    const float* __restrict__ beta_c, const float* __restrict__ logT_c,
    const float* __restrict__ logT_t, const float* __restrict__ logT_id,
    float* __restrict__ out)
{
  __shared__ float Et[C_][DTXT_];       // 51200 B
  __shared__ float Ei[C_][DID_];        // 25600 B
  __shared__ float ut_s[HID_], ui_s[HID_], wt2_s[HID_], wi2_s[HID_];
  __shared__ float sc[3][C_];           // 0: co, 1: text, 2: id
  __shared__ float invsum_s;

  const int tid = threadIdx.x;
  const int b   = blockIdx.x;

  {
    const float4* src = (const float4*)(cand_text_emb + (size_t)b*C_*DTXT_);
    float4* dst = (float4*)Et;
    for (int i = tid; i < C_*DTXT_/4; i += 256) dst[i] = src[i];
    const float4* src2 = (const float4*)(cand_id_emb + (size_t)b*C_*DID_);
    float4* dst2 = (float4*)Ei;
    for (int i = tid; i < C_*DID_/4; i += 256) dst2[i] = src2[i];
  }
  if (tid < HID_) {
    ut_s[tid]  = u_t[(size_t)b*HID_ + tid];
    ui_s[tid]  = u_i[(size_t)b*HID_ + tid];
    wt2_s[tid] = Wt2[tid];
    wi2_s[tid] = Wi2[tid];
  }
  // co-occurrence scores (already temperature-scaled)
  {
    int last_item = seq_items[(size_t)b*L_ + (lengths[b]-1)];
    float scale_c = beta_c[0] * __expf(-logT_c[0]);
    for (int c = tid; c < C_; c += 256) {
      int cid = cand_ids[(size_t)b*C_ + c];
      sc[0][c] = co_table[(size_t)last_item*V_ + cid] * scale_c;
    }
  }
  __syncthreads();

  const int jq = tid & 31, cg = tid >> 5, j0 = jq*4;
  const float invTt = __expf(-logT_t[0]);
  const float invTi = __expf(-logT_id[0]);

  // ---- text scorer: s_t[c] = sum_j Wt2[j] * relu(Wt1[j,128:256]@Et[c] + u_t[j])
  for (int p = 0; p < 4; ++p) {
    int cbase = p*32 + cg*4;
    float acc[4][4];
    #pragma unroll
    for (int cc = 0; cc < 4; ++cc)
      #pragma unroll
      for (int jj = 0; jj < 4; ++jj) acc[cc][jj] = 0.f;
    const float4* w0 = (const float4*)Wt1 + (size_t)(j0+0)*96 + 32;
    const float4* w1 = (const float4*)Wt1 + (size_t)(j0+1)*96 + 32;
    const float4* w2 = (const float4*)Wt1 + (size_t)(j0+2)*96 + 32;
    const float4* w3 = (const float4*)Wt1 + (size_t)(j0+3)*96 + 32;
    const float4* xp[4];
    #pragma unroll
    for (int cc = 0; cc < 4; ++cc) {
      int c = cbase + cc;
      xp[cc] = (const float4*)Et[c < C_ ? c : C_-1];
    }
    #pragma unroll 4
    for (int k4 = 0; k4 < 32; ++k4) {
      float4 wa = w0[k4], wb = w1[k4], wc = w2[k4], wd = w3[k4];
      #pragma unroll
      for (int cc = 0; cc < 4; ++cc) {
        float4 x = xp[cc][k4];
        acc[cc][0] += dot4(wa,x);
        acc[cc][1] += dot4(wb,x);
        acc[cc][2] += dot4(wc,x);
        acc[cc][3] += dot4(wd,x);
      }
    }
    #pragma unroll
    for (int cc = 0; cc < 4; ++cc) {
      float s = wt2_s[j0+0]*fmaxf(acc[cc][0]+ut_s[j0+0], 0.f)
              + wt2_s[j0+1]*fmaxf(acc[cc][1]+ut_s[j0+1], 0.f)
              + wt2_s[j0+2]*fmaxf(acc[cc][2]+ut_s[j0+2], 0.f)
              + wt2_s[j0+3]*fmaxf(acc[cc][3]+ut_s[j0+3], 0.f);
      s += __shfl_xor(s,16); s += __shfl_xor(s,8); s += __shfl_xor(s,4);
      s += __shfl_xor(s,2);  s += __shfl_xor(s,1);
      int c = cbase + cc;
      if (jq == 0 && c < C_) sc[1][c] = s * invTt;
    }
  }

  // ---- id scorer: s_i[c] = sum_j Wi2[j] * relu(Wi1[j,64:128]@Ei[c] + u_i[j])
  for (int p = 0; p < 4; ++p) {
    int cbase = p*32 + cg*4;
    float acc[4][4];
    #pragma unroll
    for (int cc = 0; cc < 4; ++cc)
      #pragma unroll
      for (int jj = 0; jj < 4; ++jj) acc[cc][jj] = 0.f;
    const float4* w0 = (const float4*)Wi1 + (size_t)(j0+0)*64 + 16;
    const float4* w1 = (const float4*)Wi1 + (size_t)(j0+1)*64 + 16;
    const float4* w2 = (const float4*)Wi1 + (size_t)(j0+2)*64 + 16;
    const float4* w3 = (const float4*)Wi1 + (size_t)(j0+3)*64 + 16;
    const float4* xp[4];
    #pragma unroll
    for (int cc = 0; cc < 4; ++cc) {
      int c = cbase + cc;
      xp[cc] = (const float4*)Ei[c < C_ ? c : C_-1];
    }
    #pragma unroll 2
    for (int k4 = 0; k4 < 16; ++k4) {
      float4 wa = w0[k4], wb = w1[k4], wc = w2[k4], wd = w3[k4];
      #pragma unroll
      for (int cc = 0; cc < 4; ++cc) {
        float4 x = xp[cc][k4];
        acc[cc][0] += dot4(wa,x);
        acc[cc][1] += dot4(wb,x);
        acc[cc][2] += dot4(wc,x);
        acc[cc][3] += dot4(wd,x);
      }
    }
    #pragma unroll
    for (int cc = 0; cc < 4; ++cc) {
      float s = wi2_s[j0+0]*fmaxf(acc[cc][0]+ui_s[j0+0], 0.f)
              + wi2_s[j0+1]*fmaxf(acc[cc][1]+ui_s[j0+1], 0.f)
              + wi2_s[j0+2]*fmaxf(acc[cc][2]+ui_s[j0+2], 0.f)
              + wi2_s[j0+3]*fmaxf(acc[cc][3]+ui_s[j0+3], 0.f);
      s += __shfl_xor(s,16); s += __shfl_xor(s,8); s += __shfl_xor(s,4);
      s += __shfl_xor(s,2);  s += __shfl_xor(s,1);
      int c = cbase + cc;
      if (jq == 0 && c < C_) sc[2][c] = s * invTi;
    }
  }
  __syncthreads();

  // ---- three softmaxes over C=100, one wave each (in-place, wave-synchronous)
  const int wv = tid >> 6, lane = tid & 63;
  if (wv < 3) {
    float* s = sc[wv];
    float v0 = s[lane];
    float v1 = (lane+64 < C_) ? s[lane+64] : -3.0e38f;
    float m = fmaxf(v0, v1);
    #pragma unroll
    for (int msk = 32; msk >= 1; msk >>= 1) m = fmaxf(m, __shfl_xor(m, msk));
    float e0 = __expf(v0 - m);
    float e1 = (lane+64 < C_) ? __expf(v1 - m) : 0.f;
    float su = e0 + e1;
    #pragma unroll
    for (int msk = 32; msk >= 1; msk >>= 1) su += __shfl_xor(su, msk);
    float inv = 1.f/su;
    s[lane] = e0*inv;
    if (lane+64 < C_) s[lane+64] = e1*inv;
  }
  __syncthreads();

  // ---- mix: P = (1/C + a0*Pc + a1*Pt + a2*Pid), then renormalize
  const float a0 = alp[(size_t)b*3+0];
  const float a1 = alp[(size_t)b*3+1];
  const float a2 = alp[(size_t)b*3+2];
  float v = 0.f;
  float* vals = &Et[0][0];   // Et no longer needed
  if (tid < C_) {
    v = 0.01f + a0*sc[0][tid] + a1*sc[1][tid] + a2*sc[2][tid];
    vals[tid] = v;
  }
  __syncthreads();
  if (tid < 64) {
    float x = vals[tid] + ((tid+64 < C_) ? vals[tid+64] : 0.f);
    #pragma unroll
    for (int msk = 32; msk >= 1; msk >>= 1) x += __shfl_xor(x, msk);
    if (tid == 0) invsum_s = 1.f/x;
  }
  __syncthreads();
  if (tid < C_) out[(size_t)b*C_ + tid] = v * invsum_s;
}

// ---------------------------------------------------------------------------
extern "C" void kernel_launch(void* const* d_in, const int* in_sizes, int n_in,
                              void* d_out, int out_size, void* d_ws, size_t ws_size,
                              hipStream_t stream) {
  const int*   seq_items     = (const int*)  d_in[0];
  const float* seq_id_emb    = (const float*)d_in[1];
  const float* seq_text_emb  = (const float*)d_in[2];
  const int*   lengths       = (const int*)  d_in[3];
  const int*   cand_ids      = (const int*)  d_in[4];
  const float* cand_id_emb   = (const float*)d_in[5];
  const float* cand_text_emb = (const float*)d_in[6];
  const float* co_table      = (const float*)d_in[7];
  const float* W_ih          = (const float*)d_in[8];
  const float* W_hh          = (const float*)d_in[9];
  const float* b_ih          = (const float*)d_in[10];
  const float* b_hh          = (const float*)d_in[11];
  const float* Wt1           = (const float*)d_in[12];
  const float* bt1           = (const float*)d_in[13];
  const float* Wt2           = (const float*)d_in[14];
  // d_in[15] bt2: softmax-invariant, unused
  const float* Wi1           = (const float*)d_in[16];
  const float* bi1           = (const float*)d_in[17];
  const float* Wi2           = (const float*)d_in[18];
  // d_in[19] bi2: softmax-invariant, unused
  const float* Wa1           = (const float*)d_in[20];
  const float* ba1           = (const float*)d_in[21];
  const float* Wa2           = (const float*)d_in[22];
  const float* ba2           = (const float*)d_in[23];
  // d_in[24] Wstab: P_stable = softmax(const row) = 1/C exactly, unused
  const float* beta_c        = (const float*)d_in[25];
  const float* logT_c        = (const float*)d_in[26];
  const float* logT_t        = (const float*)d_in[27];
  const float* logT_id       = (const float*)d_in[28];
  float* out = (float*)d_out;

  float* u_t = (float*)d_ws;                       // [B,128]
  float* u_i = u_t + (size_t)B_*HID_;              // [B,128]
  float* alp = u_i + (size_t)B_*HID_;              // [B,3]

  k1_gru<<<B_/8, 512, 0, stream>>>(
      lengths, seq_id_emb, seq_text_emb,
      W_ih, W_hh, b_ih, b_hh,
      Wt1, bt1, Wi1, bi1, Wa1, ba1, Wa2, ba2,
      u_t, u_i, alp);

  k2_score<<<B_, 256, 0, stream>>>(
      seq_items, lengths, cand_ids,
      cand_id_emb, cand_text_emb, co_table,
      Wt1, Wt2, Wi1, Wi2,
      u_t, u_i, alp,
      beta_c, logT_c, logT_t, logT_id,
      out);
}

// Round 2
// 937.440 us; speedup vs baseline: 1.5063x; 1.5063x over previous
//
#include <hip/hip_runtime.h>
#include <hip/hip_bf16.h>

// Problem constants (match reference setup_inputs)
constexpr int B_   = 2048;
constexpr int L_   = 200;
constexpr int C_   = 100;
constexpr int DID_ = 64;
constexpr int DTXT_= 128;
constexpr int DCTX_= 128;
constexpr int KWIN = 5;
constexpr int V_   = 2000;
constexpr int DIN_ = DID_ + DTXT_;   // 192
constexpr int HID_ = 128;

// ---------------------------------------------------------------------------
// ws layout (floats)
// ---------------------------------------------------------------------------
// u_t   : B*128
// u_i   : B*128
// alp   : B*3
// WihT  : 192*384   k-major: WihT[k*384 + row] = W_ih[row*192 + k]
// WhhT  : 128*384
// Wt1uT : 256*128   k<128: Wt1 cols 0:128 (src text); k>=128: cols 256:384 (h)
// Wt1sT : 128*128   Wt1 cols 128:256 (cand text)
// Wi1uT : 192*128   k<64: Wi1 cols 0:64 (src id); k>=64: cols 128:256 (h)
// Wi1sT :  64*128   Wi1 cols 64:128 (cand id)
// Wa1T  : 128*64

__global__ __launch_bounds__(256) void k0_transpose(
    const float* __restrict__ W_ih, const float* __restrict__ W_hh,
    const float* __restrict__ Wt1,  const float* __restrict__ Wi1,
    const float* __restrict__ Wa1,
    float* __restrict__ WihT,  float* __restrict__ WhhT,
    float* __restrict__ Wt1uT, float* __restrict__ Wt1sT,
    float* __restrict__ Wi1uT, float* __restrict__ Wi1sT,
    float* __restrict__ Wa1T)
{
  int idx = blockIdx.x*256 + threadIdx.x;
  int stride = gridDim.x*256;
  for (int i = idx; i < 192*384; i += stride) {
    int k = i/384, r = i%384; WihT[i] = W_ih[r*192 + k];
  }
  for (int i = idx; i < 128*384; i += stride) {
    int k = i/384, r = i%384; WhhT[i] = W_hh[r*128 + k];
  }
  for (int i = idx; i < 256*128; i += stride) {
    int k = i/128, j = i%128;
    Wt1uT[i] = (k < 128) ? Wt1[j*384 + k] : Wt1[j*384 + 256 + (k-128)];
  }
  for (int i = idx; i < 128*128; i += stride) {
    int k = i/128, j = i%128; Wt1sT[i] = Wt1[j*384 + 128 + k];
  }
  for (int i = idx; i < 192*128; i += stride) {
    int k = i/128, j = i%128;
    Wi1uT[i] = (k < 64) ? Wi1[j*256 + k] : Wi1[j*256 + 128 + (k-64)];
  }
  for (int i = idx; i < 64*128; i += stride) {
    int k = i/128, j = i%128; Wi1sT[i] = Wi1[j*256 + 64 + k];
  }
  for (int i = idx; i < 128*64; i += stride) {
    int k = i/64, u = i%64; Wa1T[i] = Wa1[u*128 + k];
  }
}

__device__ __forceinline__ float sigm(float x) { return 1.f/(1.f + __expf(-x)); }

// ---------------------------------------------------------------------------
// K1: GRU + u_t/u_i/alpha. 4 batches per block, 256 threads:
//   jp = tid&63 (j-pair: j0=2jp), grp = tid>>6 (batch slot).
// All W loads are k-major → lanes (jp 0..63) read 512B contiguous per wave;
// x[k] is wave-uniform (one batch per wave) → LDS broadcast.
// ---------------------------------------------------------------------------
__global__ __launch_bounds__(256) void k1_gru(
    const int*   __restrict__ lengths,
    const float* __restrict__ seq_id,
    const float* __restrict__ seq_text,
    const float* __restrict__ WihT, const float* __restrict__ WhhT,
    const float* __restrict__ b_ih, const float* __restrict__ b_hh,
    const float* __restrict__ Wt1uT, const float* __restrict__ bt1,
    const float* __restrict__ Wi1uT, const float* __restrict__ bi1,
    const float* __restrict__ Wa1T,  const float* __restrict__ ba1,
    const float* __restrict__ Wa2,   const float* __restrict__ ba2,
    float* __restrict__ u_t, float* __restrict__ u_i,
    float* __restrict__ alp)
{
  constexpr int TB = 4;
  __shared__ float xk[TB][KWIN][DIN_];   // 15360 B
  __shared__ float hbuf[2][TB][DCTX_];   //  4096 B
  __shared__ float ltext[TB][DTXT_];     //  2048 B
  __shared__ float lid[TB][DID_];        //  1024 B
  __shared__ float a1s[TB][64];          //  1024 B
  __shared__ int   s_start[TB], s_last[TB];

  const int tid = threadIdx.x;
  const int b0  = blockIdx.x * TB;

  if (tid < TB) {
    int len = lengths[b0 + tid];
    s_start[tid] = len - KWIN;
    s_last[tid]  = len - 1;
  }
  __syncthreads();

  // stage window (float4, coalesced within rows)
  for (int i = tid; i < TB*KWIN*(DID_/4); i += 256) {
    int bb = i/(KWIN*16), r = i%(KWIN*16), t = r/16, q = r%16;
    ((float4*)&xk[bb][t][0])[q] =
      ((const float4*)(seq_id + ((size_t)(b0+bb)*L_ + s_start[bb]+t)*DID_))[q];
  }
  for (int i = tid; i < TB*KWIN*(DTXT_/4); i += 256) {
    int bb = i/(KWIN*32), r = i%(KWIN*32), t = r/32, q = r%32;
    ((float4*)&xk[bb][t][DID_])[q] =
      ((const float4*)(seq_text + ((size_t)(b0+bb)*L_ + s_start[bb]+t)*DTXT_))[q];
  }
  for (int i = tid; i < TB*(DTXT_/4); i += 256) {
    int bb = i/32, q = i%32;
    ((float4*)ltext[bb])[q] =
      ((const float4*)(seq_text + ((size_t)(b0+bb)*L_ + s_last[bb])*DTXT_))[q];
  }
  for (int i = tid; i < TB*(DID_/4); i += 256) {
    int bb = i/16, q = i%16;
    ((float4*)lid[bb])[q] =
      ((const float4*)(seq_id + ((size_t)(b0+bb)*L_ + s_last[bb])*DID_))[q];
  }
  for (int i = tid; i < TB*DCTX_; i += 256) ((float*)hbuf[0])[i] = 0.f;
  __syncthreads();

  const int jp  = tid & 63;
  const int grp = tid >> 6;
  const int j0  = jp*2;
  int cur = 0;

  const float bir0 = b_ih[j0]     + b_hh[j0],     bir1 = b_ih[j0+1]     + b_hh[j0+1];
  const float biz0 = b_ih[128+j0] + b_hh[128+j0], biz1 = b_ih[128+j0+1] + b_hh[128+j0+1];
  const float bin0 = b_ih[256+j0],                bin1 = b_ih[256+j0+1];
  const float bhn0 = b_hh[256+j0],                bhn1 = b_hh[256+j0+1];

  const float* wih = WihT + j0;
  const float* whh = WhhT + j0;

  for (int t = 0; t < KWIN; ++t) {
    float ar0=bir0, ar1=bir1, az0=biz0, az1=biz1;
    float an0=bin0, an1=bin1, hn0=bhn0, hn1=bhn1;
    const float* xrow = xk[grp][t];
    #pragma unroll 8
    for (int k = 0; k < DIN_; ++k) {
      float x = xrow[k];
      float2 wr = *(const float2*)&wih[k*384];
      float2 wz = *(const float2*)&wih[k*384 + 128];
      float2 wn = *(const float2*)&wih[k*384 + 256];
      ar0 += wr.x*x; ar1 += wr.y*x;
      az0 += wz.x*x; az1 += wz.y*x;
      an0 += wn.x*x; an1 += wn.y*x;
    }
    const float* hrow = hbuf[cur][grp];
    #pragma unroll 8
    for (int k = 0; k < DCTX_; ++k) {
      float x = hrow[k];
      float2 wr = *(const float2*)&whh[k*384];
      float2 wz = *(const float2*)&whh[k*384 + 128];
      float2 wn = *(const float2*)&whh[k*384 + 256];
      ar0 += wr.x*x; ar1 += wr.y*x;
      az0 += wz.x*x; az1 += wz.y*x;
      hn0 += wn.x*x; hn1 += wn.y*x;
    }
    float r0 = sigm(ar0), r1 = sigm(ar1);
    float z0 = sigm(az0), z1 = sigm(az1);
    float n0 = tanhf(an0 + r0*hn0), n1 = tanhf(an1 + r1*hn1);
    float2 hprev = *(const float2*)&hbuf[cur][grp][j0];
    float2 hnew;
    hnew.x = (1.f - z0)*n0 + z0*hprev.x;
    hnew.y = (1.f - z1)*n1 + z1*hprev.y;
    *(float2*)&hbuf[1-cur][grp][j0] = hnew;
    __syncthreads();
    cur ^= 1;
  }
  const float* hfin = hbuf[cur][grp];

  // u_t = bt1 + Wt1[:,0:128]@last_text + Wt1[:,256:384]@h
  {
    float s0 = bt1[j0], s1 = bt1[j0+1];
    const float* w = Wt1uT + j0;
    const float* lt = ltext[grp];
    #pragma unroll 8
    for (int k = 0; k < 128; ++k) {
      float x = lt[k];
      float2 wv = *(const float2*)&w[k*128];
      s0 += wv.x*x; s1 += wv.y*x;
    }
    #pragma unroll 8
    for (int k = 0; k < 128; ++k) {
      float x = hfin[k];
      float2 wv = *(const float2*)&w[(128+k)*128];
      s0 += wv.x*x; s1 += wv.y*x;
    }
    float2 o; o.x = s0; o.y = s1;
    *(float2*)&u_t[((size_t)b0+grp)*HID_ + j0] = o;
  }
  // u_i = bi1 + Wi1[:,0:64]@last_id + Wi1[:,128:256]@h
  {
    float s0 = bi1[j0], s1 = bi1[j0+1];
    const float* w = Wi1uT + j0;
    const float* li = lid[grp];
    #pragma unroll 8
    for (int k = 0; k < 64; ++k) {
      float x = li[k];
      float2 wv = *(const float2*)&w[k*128];
      s0 += wv.x*x; s1 += wv.y*x;
    }
    #pragma unroll 8
    for (int k = 0; k < 128; ++k) {
      float x = hfin[k];
      float2 wv = *(const float2*)&w[(64+k)*128];
      s0 += wv.x*x; s1 += wv.y*x;
    }
    float2 o; o.x = s0; o.y = s1;
    *(float2*)&u_i[((size_t)b0+grp)*HID_ + j0] = o;
  }
  // alpha hidden layer (64 units, 2 per thread for jp<32)
  if (jp < 32) {
    int u0 = jp*2;
    float a0 = ba1[u0], a1 = ba1[u0+1];
    const float* w = Wa1T + u0;
    #pragma unroll 8
    for (int k = 0; k < 128; ++k) {
      float x = hfin[k];
      float2 wv = *(const float2*)&w[k*64];
      a0 += wv.x*x; a1 += wv.y*x;
    }
    a1s[grp][u0]   = fmaxf(a0, 0.f);
    a1s[grp][u0+1] = fmaxf(a1, 0.f);
  }
  __syncthreads();
  if (tid < TB) {
    int bb = tid;
    float lg0 = ba2[0], lg1 = ba2[1], lg2 = ba2[2];
    for (int k = 0; k < 64; ++k) {
      float a = a1s[bb][k];
      lg0 += Wa2[k]*a; lg1 += Wa2[64+k]*a; lg2 += Wa2[128+k]*a;
    }
    float m  = fmaxf(lg0, fmaxf(lg1, lg2));
    float e0 = __expf(lg0-m), e1 = __expf(lg1-m), e2 = __expf(lg2-m);
    float inv = 1.f/(e0+e1+e2);
    alp[((size_t)b0+bb)*3+0] = e0*inv;
    alp[((size_t)b0+bb)*3+1] = e1*inv;
    alp[((size_t)b0+bb)*3+2] = e2*inv;
  }
}

// ---------------------------------------------------------------------------
// K2: per-batch candidate scoring + 3 softmaxes + mixture + renorm.
// One block per batch, 256 threads = (jq 0..31: 4 j) x (cg 0..7: 4 cands).
// W loads k-major float4 over j (coalesced); Et/Ei broadcast from LDS.
// ---------------------------------------------------------------------------
__global__ __launch_bounds__(256) void k2_score(
    const int*   __restrict__ seq_items,
    const int*   __restrict__ lengths,
    const int*   __restrict__ cand_ids,
    const float* __restrict__ cand_id_emb,
    const float* __restrict__ cand_text_emb,
    const float* __restrict__ co_table,
    const float* __restrict__ Wt1sT, const float* __restrict__ Wt2,
    const float* __restrict__ Wi1sT, const float* __restrict__ Wi2,
    const float* __restrict__ u_t, const float* __restrict__ u_i,
    const float* __restrict__ alp,
    const float* __restrict__ beta_c, const float* __restrict__ logT_c,
    const float* __restrict__ logT_t, const float* __restrict__ logT_id,
    float* __restrict__ out)
{
  __shared__ float Et[C_][DTXT_];       // 51200 B
  __shared__ float Ei[C_][DID_];        // 25600 B
  __shared__ float ut_s[HID_], ui_s[HID_], wt2_s[HID_], wi2_s[HID_];
  __shared__ float sc[3][C_];
  __shared__ float invsum_s;

  const int tid = threadIdx.x;
  const int b   = blockIdx.x;

  {
    const float4* src = (const float4*)(cand_text_emb + (size_t)b*C_*DTXT_);
    float4* dst = (float4*)Et;
    for (int i = tid; i < C_*DTXT_/4; i += 256) dst[i] = src[i];
    const float4* src2 = (const float4*)(cand_id_emb + (size_t)b*C_*DID_);
    float4* dst2 = (float4*)Ei;
    for (int i = tid; i < C_*DID_/4; i += 256) dst2[i] = src2[i];
  }
  if (tid < HID_) {
    ut_s[tid]  = u_t[(size_t)b*HID_ + tid];
    ui_s[tid]  = u_i[(size_t)b*HID_ + tid];
    wt2_s[tid] = Wt2[tid];
    wi2_s[tid] = Wi2[tid];
  }
  {
    int last_item = seq_items[(size_t)b*L_ + (lengths[b]-1)];
    float scale_c = beta_c[0] * __expf(-logT_c[0]);
    for (int c = tid; c < C_; c += 256) {
      int cid = cand_ids[(size_t)b*C_ + c];
      sc[0][c] = co_table[(size_t)last_item*V_ + cid] * scale_c;
    }
  }
  __syncthreads();

  const int jq = tid & 31, cg = tid >> 5, j0 = jq*4;
  const float invTt = __expf(-logT_t[0]);
  const float invTi = __expf(-logT_id[0]);

  // ---- text scorer
  for (int p = 0; p < 4; ++p) {
    int cbase = p*32 + cg*4;
    float acc[4][4];
    #pragma unroll
    for (int cc = 0; cc < 4; ++cc)
      #pragma unroll
      for (int jj = 0; jj < 4; ++jj) acc[cc][jj] = 0.f;
    const float* x0 = Et[(cbase+0) < C_ ? cbase+0 : C_-1];
    const float* x1 = Et[(cbase+1) < C_ ? cbase+1 : C_-1];
    const float* x2 = Et[(cbase+2) < C_ ? cbase+2 : C_-1];
    const float* x3 = Et[(cbase+3) < C_ ? cbase+3 : C_-1];
    const float* w  = Wt1sT + j0;
    #pragma unroll 8
    for (int k = 0; k < 128; ++k) {
      float4 wv = *(const float4*)&w[k*128];
      float xa = x0[k], xb = x1[k], xc = x2[k], xd = x3[k];
      acc[0][0] += wv.x*xa; acc[0][1] += wv.y*xa; acc[0][2] += wv.z*xa; acc[0][3] += wv.w*xa;
      acc[1][0] += wv.x*xb; acc[1][1] += wv.y*xb; acc[1][2] += wv.z*xb; acc[1][3] += wv.w*xb;
      acc[2][0] += wv.x*xc; acc[2][1] += wv.y*xc; acc[2][2] += wv.z*xc; acc[2][3] += wv.w*xc;
      acc[3][0] += wv.x*xd; acc[3][1] += wv.y*xd; acc[3][2] += wv.z*xd; acc[3][3] += wv.w*xd;
    }
    #pragma unroll
    for (int cc = 0; cc < 4; ++cc) {
      float s = wt2_s[j0+0]*fmaxf(acc[cc][0]+ut_s[j0+0], 0.f)
              + wt2_s[j0+1]*fmaxf(acc[cc][1]+ut_s[j0+1], 0.f)
              + wt2_s[j0+2]*fmaxf(acc[cc][2]+ut_s[j0+2], 0.f)
              + wt2_s[j0+3]*fmaxf(acc[cc][3]+ut_s[j0+3], 0.f);
      s += __shfl_xor(s,16); s += __shfl_xor(s,8); s += __shfl_xor(s,4);
      s += __shfl_xor(s,2);  s += __shfl_xor(s,1);
      int c = cbase + cc;
      if (jq == 0 && c < C_) sc[1][c] = s * invTt;
    }
  }

  // ---- id scorer
  for (int p = 0; p < 4; ++p) {
    int cbase = p*32 + cg*4;
    float acc[4][4];
    #pragma unroll
    for (int cc = 0; cc < 4; ++cc)
      #pragma unroll
      for (int jj = 0; jj < 4; ++jj) acc[cc][jj] = 0.f;
    const float* x0 = Ei[(cbase+0) < C_ ? cbase+0 : C_-1];
    const float* x1 = Ei[(cbase+1) < C_ ? cbase+1 : C_-1];
    const float* x2 = Ei[(cbase+2) < C_ ? cbase+2 : C_-1];
    const float* x3 = Ei[(cbase+3) < C_ ? cbase+3 : C_-1];
    const float* w  = Wi1sT + j0;
    #pragma unroll 8
    for (int k = 0; k < 64; ++k) {
      float4 wv = *(const float4*)&w[k*128];
      float xa = x0[k], xb = x1[k], xc = x2[k], xd = x3[k];
      acc[0][0] += wv.x*xa; acc[0][1] += wv.y*xa; acc[0][2] += wv.z*xa; acc[0][3] += wv.w*xa;
      acc[1][0] += wv.x*xb; acc[1][1] += wv.y*xb; acc[1][2] += wv.z*xb; acc[1][3] += wv.w*xb;
      acc[2][0] += wv.x*xc; acc[2][1] += wv.y*xc; acc[2][2] += wv.z*xc; acc[2][3] += wv.w*xc;
      acc[3][0] += wv.x*xd; acc[3][1] += wv.y*xd; acc[3][2] += wv.z*xd; acc[3][3] += wv.w*xd;
    }
    #pragma unroll
    for (int cc = 0; cc < 4; ++cc) {
      float s = wi2_s[j0+0]*fmaxf(acc[cc][0]+ui_s[j0+0], 0.f)
              + wi2_s[j0+1]*fmaxf(acc[cc][1]+ui_s[j0+1], 0.f)
              + wi2_s[j0+2]*fmaxf(acc[cc][2]+ui_s[j0+2], 0.f)
              + wi2_s[j0+3]*fmaxf(acc[cc][3]+ui_s[j0+3], 0.f);
      s += __shfl_xor(s,16); s += __shfl_xor(s,8); s += __shfl_xor(s,4);
      s += __shfl_xor(s,2);  s += __shfl_xor(s,1);
      int c = cbase + cc;
      if (jq == 0 && c < C_) sc[2][c] = s * invTi;
    }
  }
  __syncthreads();

  // ---- three softmaxes over C=100, one wave each
  const int wv = tid >> 6, lane = tid & 63;
  if (wv < 3) {
    float* s = sc[wv];
    float v0 = s[lane];
    float v1 = (lane+64 < C_) ? s[lane+64] : -3.0e38f;
    float m = fmaxf(v0, v1);
    #pragma unroll
    for (int msk = 32; msk >= 1; msk >>= 1) m = fmaxf(m, __shfl_xor(m, msk));
    float e0 = __expf(v0 - m);
    float e1 = (lane+64 < C_) ? __expf(v1 - m) : 0.f;
    float su = e0 + e1;
    #pragma unroll
    for (int msk = 32; msk >= 1; msk >>= 1) su += __shfl_xor(su, msk);
    float inv = 1.f/su;
    s[lane] = e0*inv;
    if (lane+64 < C_) s[lane+64] = e1*inv;
  }
  __syncthreads();

  // ---- mix: P = (1/C + a0*Pc + a1*Pt + a2*Pid), then renormalize
  const float a0 = alp[(size_t)b*3+0];
  const float a1 = alp[(size_t)b*3+1];
  const float a2 = alp[(size_t)b*3+2];
  float v = 0.f;
  float* vals = &Et[0][0];
  if (tid < C_) {
    v = 0.01f + a0*sc[0][tid] + a1*sc[1][tid] + a2*sc[2][tid];
    vals[tid] = v;
  }
  __syncthreads();
  if (tid < 64) {
    float x = vals[tid] + ((tid+64 < C_) ? vals[tid+64] : 0.f);
    #pragma unroll
    for (int msk = 32; msk >= 1; msk >>= 1) x += __shfl_xor(x, msk);
    if (tid == 0) invsum_s = 1.f/x;
  }
  __syncthreads();
  if (tid < C_) out[(size_t)b*C_ + tid] = v * invsum_s;
}

// ---------------------------------------------------------------------------
extern "C" void kernel_launch(void* const* d_in, const int* in_sizes, int n_in,
                              void* d_out, int out_size, void* d_ws, size_t ws_size,
                              hipStream_t stream) {
  const int*   seq_items     = (const int*)  d_in[0];
  const float* seq_id_emb    = (const float*)d_in[1];
  const float* seq_text_emb  = (const float*)d_in[2];
  const int*   lengths       = (const int*)  d_in[3];
  const int*   cand_ids      = (const int*)  d_in[4];
  const float* cand_id_emb   = (const float*)d_in[5];
  const float* cand_text_emb = (const float*)d_in[6];
  const float* co_table      = (const float*)d_in[7];
  const float* W_ih          = (const float*)d_in[8];
  const float* W_hh          = (const float*)d_in[9];
  const float* b_ih          = (const float*)d_in[10];
  const float* b_hh          = (const float*)d_in[11];
  const float* Wt1           = (const float*)d_in[12];
  const float* bt1           = (const float*)d_in[13];
  const float* Wt2           = (const float*)d_in[14];
  const float* Wi1           = (const float*)d_in[16];
  const float* bi1           = (const float*)d_in[17];
  const float* Wi2           = (const float*)d_in[18];
  const float* Wa1           = (const float*)d_in[20];
  const float* ba1           = (const float*)d_in[21];
  const float* Wa2           = (const float*)d_in[22];
  const float* ba2           = (const float*)d_in[23];
  const float* beta_c        = (const float*)d_in[25];
  const float* logT_c        = (const float*)d_in[26];
  const float* logT_t        = (const float*)d_in[27];
  const float* logT_id       = (const float*)d_in[28];
  float* out = (float*)d_out;

  float* p = (float*)d_ws;
  float* u_t   = p; p += (size_t)B_*HID_;
  float* u_i   = p; p += (size_t)B_*HID_;
  float* alp   = p; p += (size_t)B_*3;
  float* WihT  = p; p += 192*384;
  float* WhhT  = p; p += 128*384;
  float* Wt1uT = p; p += 256*128;
  float* Wt1sT = p; p += 128*128;
  float* Wi1uT = p; p += 192*128;
  float* Wi1sT = p; p += 64*128;
  float* Wa1T  = p; p += 128*64;

  k0_transpose<<<128, 256, 0, stream>>>(
      W_ih, W_hh, Wt1, Wi1, Wa1,
      WihT, WhhT, Wt1uT, Wt1sT, Wi1uT, Wi1sT, Wa1T);

  k1_gru<<<B_/4, 256, 0, stream>>>(
      lengths, seq_id_emb, seq_text_emb,
      WihT, WhhT, b_ih, b_hh,
      Wt1uT, bt1, Wi1uT, bi1, Wa1T, ba1, Wa2, ba2,
      u_t, u_i, alp);

  k2_score<<<B_, 256, 0, stream>>>(
      seq_items, lengths, cand_ids,
      cand_id_emb, cand_text_emb, co_table,
      Wt1sT, Wt2, Wi1sT, Wi2,
      u_t, u_i, alp,
      beta_c, logT_c, logT_t, logT_id,
      out);
}

// Round 3
// 722.682 us; speedup vs baseline: 1.9539x; 1.2972x over previous
//
#include <hip/hip_runtime.h>
#include <hip/hip_bf16.h>

// Problem constants (match reference setup_inputs)
constexpr int B_   = 2048;
constexpr int L_   = 200;
constexpr int C_   = 100;
constexpr int DID_ = 64;
constexpr int DTXT_= 128;
constexpr int DCTX_= 128;
constexpr int KWIN = 5;
constexpr int V_   = 2000;
constexpr int DIN_ = DID_ + DTXT_;   // 192
constexpr int HID_ = 128;
constexpr int TB   = 4;              // batches per k1 block

// ---------------------------------------------------------------------------
// ws layout (floats): u_t B*128 | u_i B*128 | alp B*3 | WihT 192*384 |
// WhhT 128*384 | Wt1uT 256*128 | Wt1sT 128*128 | Wi1uT 192*128 |
// Wi1sT 64*128 | Wa1T 128*64
// k-major transposes: WT[k*rows + row] = W[row*K + k]

__global__ __launch_bounds__(256) void k0_transpose(
    const float* __restrict__ W_ih, const float* __restrict__ W_hh,
    const float* __restrict__ Wt1,  const float* __restrict__ Wi1,
    const float* __restrict__ Wa1,
    float* __restrict__ WihT,  float* __restrict__ WhhT,
    float* __restrict__ Wt1uT, float* __restrict__ Wt1sT,
    float* __restrict__ Wi1uT, float* __restrict__ Wi1sT,
    float* __restrict__ Wa1T)
{
  int idx = blockIdx.x*256 + threadIdx.x;
  int stride = gridDim.x*256;
  for (int i = idx; i < 192*384; i += stride) {
    int k = i/384, r = i%384; WihT[i] = W_ih[r*192 + k];
  }
  for (int i = idx; i < 128*384; i += stride) {
    int k = i/384, r = i%384; WhhT[i] = W_hh[r*128 + k];
  }
  for (int i = idx; i < 256*128; i += stride) {
    int k = i/128, j = i%128;
    Wt1uT[i] = (k < 128) ? Wt1[j*384 + k] : Wt1[j*384 + 256 + (k-128)];
  }
  for (int i = idx; i < 128*128; i += stride) {
    int k = i/128, j = i%128; Wt1sT[i] = Wt1[j*384 + 128 + k];
  }
  for (int i = idx; i < 192*128; i += stride) {
    int k = i/128, j = i%128;
    Wi1uT[i] = (k < 64) ? Wi1[j*256 + k] : Wi1[j*256 + 128 + (k-64)];
  }
  for (int i = idx; i < 64*128; i += stride) {
    int k = i/128, j = i%128; Wi1sT[i] = Wi1[j*256 + 64 + k];
  }
  for (int i = idx; i < 128*64; i += stride) {
    int k = i/64, u = i%64; Wa1T[i] = Wa1[u*128 + k];
  }
}

__device__ __forceinline__ float sigm(float x) { return 1.f/(1.f + __expf(-x)); }

// ---------------------------------------------------------------------------
// K1: GRU + heads, weight reads amortized over TB batches and (for W_ih) all
// 5 timesteps. Thread tid<192 owns output-row pair r0=2tid of the 384 rows.
// Weights streamed k-major (coalesced, once per block per use); activations
// broadcast from LDS (wave-uniform b128 reads, conflict-free).
// ---------------------------------------------------------------------------
__global__ __launch_bounds__(256) void k1_gru(
    const int*   __restrict__ lengths,
    const float* __restrict__ seq_id,
    const float* __restrict__ seq_text,
    const float* __restrict__ WihT, const float* __restrict__ WhhT,
    const float* __restrict__ b_ih, const float* __restrict__ b_hh,
    const float* __restrict__ Wt1uT, const float* __restrict__ bt1,
    const float* __restrict__ Wi1uT, const float* __restrict__ bi1,
    const float* __restrict__ Wa1T,  const float* __restrict__ ba1,
    const float* __restrict__ Wa2,   const float* __restrict__ ba2,
    float* __restrict__ u_t, float* __restrict__ u_i,
    float* __restrict__ alp)
{
  __shared__ float xk[TB][KWIN][DIN_];       // 15360 B
  __shared__ float G[KWIN*TB*384];           // 30720 B  input projections
  __shared__ float Hacc[TB][384];            //  6144 B  per-t hidden proj
  __shared__ float hbuf[2][TB][DCTX_];       //  4096 B
  __shared__ float ltext[TB][DTXT_];         //  2048 B
  __shared__ float lid[TB][DID_];            //  1024 B
  __shared__ float a1s[TB][64];              //  1024 B
  __shared__ int   s_start[TB], s_last[TB];

  const int tid = threadIdx.x;
  const int b0  = blockIdx.x * TB;

  if (tid < TB) {
    int len = lengths[b0 + tid];
    s_start[tid] = len - KWIN;
    s_last[tid]  = len - 1;
  }
  __syncthreads();

  // ---- stage inputs (coalesced float4 within rows)
  for (int i = tid; i < TB*KWIN*(DID_/4); i += 256) {
    int bb = i/(KWIN*16), r = i%(KWIN*16), t = r/16, q = r%16;
    ((float4*)&xk[bb][t][0])[q] =
      ((const float4*)(seq_id + ((size_t)(b0+bb)*L_ + s_start[bb]+t)*DID_))[q];
  }
  for (int i = tid; i < TB*KWIN*(DTXT_/4); i += 256) {
    int bb = i/(KWIN*32), r = i%(KWIN*32), t = r/32, q = r%32;
    ((float4*)&xk[bb][t][DID_])[q] =
      ((const float4*)(seq_text + ((size_t)(b0+bb)*L_ + s_start[bb]+t)*DTXT_))[q];
  }
  for (int i = tid; i < TB*(DTXT_/4); i += 256) {
    int bb = i/32, q = i%32;
    ((float4*)ltext[bb])[q] =
      ((const float4*)(seq_text + ((size_t)(b0+bb)*L_ + s_last[bb])*DTXT_))[q];
  }
  for (int i = tid; i < TB*(DID_/4); i += 256) {
    int bb = i/16, q = i%16;
    ((float4*)lid[bb])[q] =
      ((const float4*)(seq_id + ((size_t)(b0+bb)*L_ + s_last[bb])*DID_))[q];
  }
  for (int i = tid; i < TB*DCTX_; i += 256) ((float*)hbuf[0])[i] = 0.f;
  __syncthreads();

  // ---- Phase A: input projections for all 5 steps, WihT read ONCE per block
  if (tid < 192) {
    const int r0 = 2*tid;
    float acc[KWIN][TB][2];
    const float bi0 = b_ih[r0], bi1v = b_ih[r0+1];
    #pragma unroll
    for (int t = 0; t < KWIN; ++t)
      #pragma unroll
      for (int bb = 0; bb < TB; ++bb) { acc[t][bb][0] = bi0; acc[t][bb][1] = bi1v; }
    const float* w = WihT + r0;
    for (int k4 = 0; k4 < DIN_; k4 += 4) {
      float2 w0 = *(const float2*)&w[(size_t)(k4+0)*384];
      float2 w1 = *(const float2*)&w[(size_t)(k4+1)*384];
      float2 w2 = *(const float2*)&w[(size_t)(k4+2)*384];
      float2 w3 = *(const float2*)&w[(size_t)(k4+3)*384];
      #pragma unroll
      for (int t = 0; t < KWIN; ++t)
        #pragma unroll
        for (int bb = 0; bb < TB; ++bb) {
          float4 x = *(const float4*)&xk[bb][t][k4];
          acc[t][bb][0] += w0.x*x.x + w1.x*x.y + w2.x*x.z + w3.x*x.w;
          acc[t][bb][1] += w0.y*x.x + w1.y*x.y + w2.y*x.z + w3.y*x.w;
        }
    }
    #pragma unroll
    for (int t = 0; t < KWIN; ++t)
      #pragma unroll
      for (int bb = 0; bb < TB; ++bb) {
        float2 o; o.x = acc[t][bb][0]; o.y = acc[t][bb][1];
        *(float2*)&G[(size_t)(t*TB+bb)*384 + r0] = o;
      }
  }
  __syncthreads();

  // ---- Phase B: 5 recurrent steps, WhhT read once per block per step
  int cur = 0;
  for (int t = 0; t < KWIN; ++t) {
    if (tid < 192) {
      const int r0 = 2*tid;
      float acc[TB][2];
      const float bh0 = b_hh[r0], bh1 = b_hh[r0+1];
      #pragma unroll
      for (int bb = 0; bb < TB; ++bb) { acc[bb][0] = bh0; acc[bb][1] = bh1; }
      const float* w = WhhT + r0;
      for (int k4 = 0; k4 < DCTX_; k4 += 4) {
        float2 w0 = *(const float2*)&w[(size_t)(k4+0)*384];
        float2 w1 = *(const float2*)&w[(size_t)(k4+1)*384];
        float2 w2 = *(const float2*)&w[(size_t)(k4+2)*384];
        float2 w3 = *(const float2*)&w[(size_t)(k4+3)*384];
        #pragma unroll
        for (int bb = 0; bb < TB; ++bb) {
          float4 x = *(const float4*)&hbuf[cur][bb][k4];
          acc[bb][0] += w0.x*x.x + w1.x*x.y + w2.x*x.z + w3.x*x.w;
          acc[bb][1] += w0.y*x.x + w1.y*x.y + w2.y*x.z + w3.y*x.w;
        }
      }
      #pragma unroll
      for (int bb = 0; bb < TB; ++bb) {
        float2 o; o.x = acc[bb][0]; o.y = acc[bb][1];
        *(float2*)&Hacc[bb][r0] = o;
      }
    }
    __syncthreads();
    // gate nonlinearity: 128 j x 4 bb = 512 items over 256 threads
    {
      const int j   = tid & 127;
      const int bb0 = (tid >> 7) * 2;
      #pragma unroll
      for (int e = 0; e < 2; ++e) {
        int bb = bb0 + e;
        const float* g = &G[(size_t)(t*TB+bb)*384];
        float i_r = g[j], i_z = g[128+j], i_n = g[256+j];
        float h_r = Hacc[bb][j], h_z = Hacc[bb][128+j], h_n = Hacc[bb][256+j];
        float r  = sigm(i_r + h_r);
        float zg = sigm(i_z + h_z);
        float n  = tanhf(i_n + r*h_n);
        hbuf[1-cur][bb][j] = (1.f - zg)*n + zg*hbuf[cur][bb][j];
      }
    }
    __syncthreads();
    cur ^= 1;
  }
  const float (*hf)[DCTX_] = hbuf[cur];

  // ---- Phase C: heads in parallel across waves
  if (tid < 64) {
    // u_t = bt1 + Wt1[:,0:128]@last_text + Wt1[:,256:384]@h
    const int j0 = 2*tid;
    float acc[TB][2];
    const float bb0v = bt1[j0], bb1v = bt1[j0+1];
    #pragma unroll
    for (int bb = 0; bb < TB; ++bb) { acc[bb][0] = bb0v; acc[bb][1] = bb1v; }
    const float* w = Wt1uT + j0;
    for (int k4 = 0; k4 < 128; k4 += 4) {
      float2 w0 = *(const float2*)&w[(size_t)(k4+0)*128];
      float2 w1 = *(const float2*)&w[(size_t)(k4+1)*128];
      float2 w2 = *(const float2*)&w[(size_t)(k4+2)*128];
      float2 w3 = *(const float2*)&w[(size_t)(k4+3)*128];
      #pragma unroll
      for (int bb = 0; bb < TB; ++bb) {
        float4 x = *(const float4*)&ltext[bb][k4];
        acc[bb][0] += w0.x*x.x + w1.x*x.y + w2.x*x.z + w3.x*x.w;
        acc[bb][1] += w0.y*x.x + w1.y*x.y + w2.y*x.z + w3.y*x.w;
      }
    }
    for (int k4 = 0; k4 < 128; k4 += 4) {
      float2 w0 = *(const float2*)&w[(size_t)(128+k4+0)*128];
      float2 w1 = *(const float2*)&w[(size_t)(128+k4+1)*128];
      float2 w2 = *(const float2*)&w[(size_t)(128+k4+2)*128];
      float2 w3 = *(const float2*)&w[(size_t)(128+k4+3)*128];
      #pragma unroll
      for (int bb = 0; bb < TB; ++bb) {
        float4 x = *(const float4*)&hf[bb][k4];
        acc[bb][0] += w0.x*x.x + w1.x*x.y + w2.x*x.z + w3.x*x.w;
        acc[bb][1] += w0.y*x.x + w1.y*x.y + w2.y*x.z + w3.y*x.w;
      }
    }
    #pragma unroll
    for (int bb = 0; bb < TB; ++bb) {
      float2 o; o.x = acc[bb][0]; o.y = acc[bb][1];
      *(float2*)&u_t[((size_t)b0+bb)*HID_ + j0] = o;
    }
  } else if (tid < 128) {
    // u_i = bi1 + Wi1[:,0:64]@last_id + Wi1[:,128:256]@h
    const int j0 = 2*(tid-64);
    float acc[TB][2];
    const float bb0v = bi1[j0], bb1v = bi1[j0+1];
    #pragma unroll
    for (int bb = 0; bb < TB; ++bb) { acc[bb][0] = bb0v; acc[bb][1] = bb1v; }
    const float* w = Wi1uT + j0;
    for (int k4 = 0; k4 < 64; k4 += 4) {
      float2 w0 = *(const float2*)&w[(size_t)(k4+0)*128];
      float2 w1 = *(const float2*)&w[(size_t)(k4+1)*128];
      float2 w2 = *(const float2*)&w[(size_t)(k4+2)*128];
      float2 w3 = *(const float2*)&w[(size_t)(k4+3)*128];
      #pragma unroll
      for (int bb = 0; bb < TB; ++bb) {
        float4 x = *(const float4*)&lid[bb][k4];
        acc[bb][0] += w0.x*x.x + w1.x*x.y + w2.x*x.z + w3.x*x.w;
        acc[bb][1] += w0.y*x.x + w1.y*x.y + w2.y*x.z + w3.y*x.w;
      }
    }
    for (int k4 = 0; k4 < 128; k4 += 4) {
      float2 w0 = *(const float2*)&w[(size_t)(64+k4+0)*128];
      float2 w1 = *(const float2*)&w[(size_t)(64+k4+1)*128];
      float2 w2 = *(const float2*)&w[(size_t)(64+k4+2)*128];
      float2 w3 = *(const float2*)&w[(size_t)(64+k4+3)*128];
      #pragma unroll
      for (int bb = 0; bb < TB; ++bb) {
        float4 x = *(const float4*)&hf[bb][k4];
        acc[bb][0] += w0.x*x.x + w1.x*x.y + w2.x*x.z + w3.x*x.w;
        acc[bb][1] += w0.y*x.x + w1.y*x.y + w2.y*x.z + w3.y*x.w;
      }
    }
    #pragma unroll
    for (int bb = 0; bb < TB; ++bb) {
      float2 o; o.x = acc[bb][0]; o.y = acc[bb][1];
      *(float2*)&u_i[((size_t)b0+bb)*HID_ + j0] = o;
    }
  } else if (tid < 160) {
    // alpha hidden: 64 units, rows 2*(tid-128)
    const int u0 = 2*(tid-128);
    float acc[TB][2];
    const float bb0v = ba1[u0], bb1v = ba1[u0+1];
    #pragma unroll
    for (int bb = 0; bb < TB; ++bb) { acc[bb][0] = bb0v; acc[bb][1] = bb1v; }
    const float* w = Wa1T + u0;
    for (int k4 = 0; k4 < 128; k4 += 4) {
      float2 w0 = *(const float2*)&w[(size_t)(k4+0)*64];
      float2 w1 = *(const float2*)&w[(size_t)(k4+1)*64];
      float2 w2 = *(const float2*)&w[(size_t)(k4+2)*64];
      float2 w3 = *(const float2*)&w[(size_t)(k4+3)*64];
      #pragma unroll
      for (int bb = 0; bb < TB; ++bb) {
        float4 x = *(const float4*)&hf[bb][k4];
        acc[bb][0] += w0.x*x.x + w1.x*x.y + w2.x*x.z + w3.x*x.w;
        acc[bb][1] += w0.y*x.x + w1.y*x.y + w2.y*x.z + w3.y*x.w;
      }
    }
    #pragma unroll
    for (int bb = 0; bb < TB; ++bb) {
      a1s[bb][u0]   = fmaxf(acc[bb][0], 0.f);
      a1s[bb][u0+1] = fmaxf(acc[bb][1], 0.f);
    }
  }
  __syncthreads();
  if (tid < TB) {
    int bb = tid;
    float lg0 = ba2[0], lg1 = ba2[1], lg2 = ba2[2];
    for (int k = 0; k < 64; ++k) {
      float a = a1s[bb][k];
      lg0 += Wa2[k]*a; lg1 += Wa2[64+k]*a; lg2 += Wa2[128+k]*a;
    }
    float m  = fmaxf(lg0, fmaxf(lg1, lg2));
    float e0 = __expf(lg0-m), e1 = __expf(lg1-m), e2 = __expf(lg2-m);
    float inv = 1.f/(e0+e1+e2);
    alp[((size_t)b0+bb)*3+0] = e0*inv;
    alp[((size_t)b0+bb)*3+1] = e1*inv;
    alp[((size_t)b0+bb)*3+2] = e2*inv;
  }
}

// ---------------------------------------------------------------------------
// K2: per-batch candidate scoring + 3 softmaxes + mixture + renorm.
// One block per batch, 256 threads = (jq 0..31: 4 j) x (cg 0..7: 4 cands).
// k-blocked x4: float4 weight loads over j, b128 LDS x reads over k.
// ---------------------------------------------------------------------------
__global__ __launch_bounds__(256) void k2_score(
    const int*   __restrict__ seq_items,
    const int*   __restrict__ lengths,
    const int*   __restrict__ cand_ids,
    const float* __restrict__ cand_id_emb,
    const float* __restrict__ cand_text_emb,
    const float* __restrict__ co_table,
    const float* __restrict__ Wt1sT, const float* __restrict__ Wt2,
    const float* __restrict__ Wi1sT, const float* __restrict__ Wi2,
    const float* __restrict__ u_t, const float* __restrict__ u_i,
    const float* __restrict__ alp,
    const float* __restrict__ beta_c, const float* __restrict__ logT_c,
    const float* __restrict__ logT_t, const float* __restrict__ logT_id,
    float* __restrict__ out)
{
  __shared__ float Et[C_][DTXT_];       // 51200 B
  __shared__ float Ei[C_][DID_];        // 25600 B
  __shared__ float ut_s[HID_], ui_s[HID_], wt2_s[HID_], wi2_s[HID_];
  __shared__ float sc[3][C_];
  __shared__ float invsum_s;

  const int tid = threadIdx.x;
  const int b   = blockIdx.x;

  {
    const float4* src = (const float4*)(cand_text_emb + (size_t)b*C_*DTXT_);
    float4* dst = (float4*)Et;
    for (int i = tid; i < C_*DTXT_/4; i += 256) dst[i] = src[i];
    const float4* src2 = (const float4*)(cand_id_emb + (size_t)b*C_*DID_);
    float4* dst2 = (float4*)Ei;
    for (int i = tid; i < C_*DID_/4; i += 256) dst2[i] = src2[i];
  }
  if (tid < HID_) {
    ut_s[tid]  = u_t[(size_t)b*HID_ + tid];
    ui_s[tid]  = u_i[(size_t)b*HID_ + tid];
    wt2_s[tid] = Wt2[tid];
    wi2_s[tid] = Wi2[tid];
  }
  {
    int last_item = seq_items[(size_t)b*L_ + (lengths[b]-1)];
    float scale_c = beta_c[0] * __expf(-logT_c[0]);
    for (int c = tid; c < C_; c += 256) {
      int cid = cand_ids[(size_t)b*C_ + c];
      sc[0][c] = co_table[(size_t)last_item*V_ + cid] * scale_c;
    }
  }
  __syncthreads();

  const int jq = tid & 31, cg = tid >> 5, j0 = jq*4;
  const float invTt = __expf(-logT_t[0]);
  const float invTi = __expf(-logT_id[0]);

  // ---- text scorer
  for (int p = 0; p < 4; ++p) {
    int cbase = p*32 + cg*4;
    float acc[4][4];
    #pragma unroll
    for (int cc = 0; cc < 4; ++cc)
      #pragma unroll
      for (int jj = 0; jj < 4; ++jj) acc[cc][jj] = 0.f;
    const float* x0 = Et[(cbase+0) < C_ ? cbase+0 : C_-1];
    const float* x1 = Et[(cbase+1) < C_ ? cbase+1 : C_-1];
    const float* x2 = Et[(cbase+2) < C_ ? cbase+2 : C_-1];
    const float* x3 = Et[(cbase+3) < C_ ? cbase+3 : C_-1];
    const float* w  = Wt1sT + j0;
    for (int k4 = 0; k4 < 128; k4 += 4) {
      float4 w0 = *(const float4*)&w[(size_t)(k4+0)*128];
      float4 w1 = *(const float4*)&w[(size_t)(k4+1)*128];
      float4 w2 = *(const float4*)&w[(size_t)(k4+2)*128];
      float4 w3 = *(const float4*)&w[(size_t)(k4+3)*128];
      float4 xa = *(const float4*)&x0[k4];
      float4 xb = *(const float4*)&x1[k4];
      float4 xc = *(const float4*)&x2[k4];
      float4 xd = *(const float4*)&x3[k4];
      #pragma unroll
      for (int jj = 0; jj < 4; ++jj) {
        float wva = (&w0.x)[jj], wvb = (&w1.x)[jj], wvc = (&w2.x)[jj], wvd = (&w3.x)[jj];
        acc[0][jj] += wva*xa.x + wvb*xa.y + wvc*xa.z + wvd*xa.w;
        acc[1][jj] += wva*xb.x + wvb*xb.y + wvc*xb.z + wvd*xb.w;
        acc[2][jj] += wva*xc.x + wvb*xc.y + wvc*xc.z + wvd*xc.w;
        acc[3][jj] += wva*xd.x + wvb*xd.y + wvc*xd.z + wvd*xd.w;
      }
    }
    #pragma unroll
    for (int cc = 0; cc < 4; ++cc) {
      float s = wt2_s[j0+0]*fmaxf(acc[cc][0]+ut_s[j0+0], 0.f)
              + wt2_s[j0+1]*fmaxf(acc[cc][1]+ut_s[j0+1], 0.f)
              + wt2_s[j0+2]*fmaxf(acc[cc][2]+ut_s[j0+2], 0.f)
              + wt2_s[j0+3]*fmaxf(acc[cc][3]+ut_s[j0+3], 0.f);
      s += __shfl_xor(s,16); s += __shfl_xor(s,8); s += __shfl_xor(s,4);
      s += __shfl_xor(s,2);  s += __shfl_xor(s,1);
      int c = cbase + cc;
      if (jq == 0 && c < C_) sc[1][c] = s * invTt;
    }
  }

  // ---- id scorer
  for (int p = 0; p < 4; ++p) {
    int cbase = p*32 + cg*4;
    float acc[4][4];
    #pragma unroll
    for (int cc = 0; cc < 4; ++cc)
      #pragma unroll
      for (int jj = 0; jj < 4; ++jj) acc[cc][jj] = 0.f;
    const float* x0 = Ei[(cbase+0) < C_ ? cbase+0 : C_-1];
    const float* x1 = Ei[(cbase+1) < C_ ? cbase+1 : C_-1];
    const float* x2 = Ei[(cbase+2) < C_ ? cbase+2 : C_-1];
    const float* x3 = Ei[(cbase+3) < C_ ? cbase+3 : C_-1];
    const float* w  = Wi1sT + j0;
    for (int k4 = 0; k4 < 64; k4 += 4) {
      float4 w0 = *(const float4*)&w[(size_t)(k4+0)*128];
      float4 w1 = *(const float4*)&w[(size_t)(k4+1)*128];
      float4 w2 = *(const float4*)&w[(size_t)(k4+2)*128];
      float4 w3 = *(const float4*)&w[(size_t)(k4+3)*128];
      float4 xa = *(const float4*)&x0[k4];
      float4 xb = *(const float4*)&x1[k4];
      float4 xc = *(const float4*)&x2[k4];
      float4 xd = *(const float4*)&x3[k4];
      #pragma unroll
      for (int jj = 0; jj < 4; ++jj) {
        float wva = (&w0.x)[jj], wvb = (&w1.x)[jj], wvc = (&w2.x)[jj], wvd = (&w3.x)[jj];
        acc[0][jj] += wva*xa.x + wvb*xa.y + wvc*xa.z + wvd*xa.w;
        acc[1][jj] += wva*xb.x + wvb*xb.y + wvc*xb.z + wvd*xb.w;
        acc[2][jj] += wva*xc.x + wvb*xc.y + wvc*xc.z + wvd*xc.w;
        acc[3][jj] += wva*xd.x + wvb*xd.y + wvc*xd.z + wvd*xd.w;
      }
    }
    #pragma unroll
    for (int cc = 0; cc < 4; ++cc) {
      float s = wi2_s[j0+0]*fmaxf(acc[cc][0]+ui_s[j0+0], 0.f)
              + wi2_s[j0+1]*fmaxf(acc[cc][1]+ui_s[j0+1], 0.f)
              + wi2_s[j0+2]*fmaxf(acc[cc][2]+ui_s[j0+2], 0.f)
              + wi2_s[j0+3]*fmaxf(acc[cc][3]+ui_s[j0+3], 0.f);
      s += __shfl_xor(s,16); s += __shfl_xor(s,8); s += __shfl_xor(s,4);
      s += __shfl_xor(s,2);  s += __shfl_xor(s,1);
      int c = cbase + cc;
      if (jq == 0 && c < C_) sc[2][c] = s * invTi;
    }
  }
  __syncthreads();

  // ---- three softmaxes over C=100, one wave each
  const int wv = tid >> 6, lane = tid & 63;
  if (wv < 3) {
    float* s = sc[wv];
    float v0 = s[lane];
    float v1 = (lane+64 < C_) ? s[lane+64] : -3.0e38f;
    float m = fmaxf(v0, v1);
    #pragma unroll
    for (int msk = 32; msk >= 1; msk >>= 1) m = fmaxf(m, __shfl_xor(m, msk));
    float e0 = __expf(v0 - m);
    float e1 = (lane+64 < C_) ? __expf(v1 - m) : 0.f;
    float su = e0 + e1;
    #pragma unroll
    for (int msk = 32; msk >= 1; msk >>= 1) su += __shfl_xor(su, msk);
    float inv = 1.f/su;
    s[lane] = e0*inv;
    if (lane+64 < C_) s[lane+64] = e1*inv;
  }
  __syncthreads();

  // ---- mix: P = (1/C + a0*Pc + a1*Pt + a2*Pid), then renormalize
  const float a0 = alp[(size_t)b*3+0];
  const float a1 = alp[(size_t)b*3+1];
  const float a2 = alp[(size_t)b*3+2];
  float v = 0.f;
  float* vals = &Et[0][0];
  if (tid < C_) {
    v = 0.01f + a0*sc[0][tid] + a1*sc[1][tid] + a2*sc[2][tid];
    vals[tid] = v;
  }
  __syncthreads();
  if (tid < 64) {
    float x = vals[tid] + ((tid+64 < C_) ? vals[tid+64] : 0.f);
    #pragma unroll
    for (int msk = 32; msk >= 1; msk >>= 1) x += __shfl_xor(x, msk);
    if (tid == 0) invsum_s = 1.f/x;
  }
  __syncthreads();
  if (tid < C_) out[(size_t)b*C_ + tid] = v * invsum_s;
}

// ---------------------------------------------------------------------------
extern "C" void kernel_launch(void* const* d_in, const int* in_sizes, int n_in,
                              void* d_out, int out_size, void* d_ws, size_t ws_size,
                              hipStream_t stream) {
  const int*   seq_items     = (const int*)  d_in[0];
  const float* seq_id_emb    = (const float*)d_in[1];
  const float* seq_text_emb  = (const float*)d_in[2];
  const int*   lengths       = (const int*)  d_in[3];
  const int*   cand_ids      = (const int*)  d_in[4];
  const float* cand_id_emb   = (const float*)d_in[5];
  const float* cand_text_emb = (const float*)d_in[6];
  const float* co_table      = (const float*)d_in[7];
  const float* W_ih          = (const float*)d_in[8];
  const float* W_hh          = (const float*)d_in[9];
  const float* b_ih          = (const float*)d_in[10];
  const float* b_hh          = (const float*)d_in[11];
  const float* Wt1           = (const float*)d_in[12];
  const float* bt1           = (const float*)d_in[13];
  const float* Wt2           = (const float*)d_in[14];
  const float* Wi1           = (const float*)d_in[16];
  const float* bi1           = (const float*)d_in[17];
  const float* Wi2           = (const float*)d_in[18];
  const float* Wa1           = (const float*)d_in[20];
  const float* ba1           = (const float*)d_in[21];
  const float* Wa2           = (const float*)d_in[22];
  const float* ba2           = (const float*)d_in[23];
  const float* beta_c        = (const float*)d_in[25];
  const float* logT_c        = (const float*)d_in[26];
  const float* logT_t        = (const float*)d_in[27];
  const float* logT_id       = (const float*)d_in[28];
  float* out = (float*)d_out;

  float* p = (float*)d_ws;
  float* u_t   = p; p += (size_t)B_*HID_;
  float* u_i   = p; p += (size_t)B_*HID_;
  float* alp   = p; p += (size_t)B_*3;
  float* WihT  = p; p += 192*384;
  float* WhhT  = p; p += 128*384;
  float* Wt1uT = p; p += 256*128;
  float* Wt1sT = p; p += 128*128;
  float* Wi1uT = p; p += 192*128;
  float* Wi1sT = p; p += 64*128;
  float* Wa1T  = p; p += 128*64;

  k0_transpose<<<128, 256, 0, stream>>>(
      W_ih, W_hh, Wt1, Wi1, Wa1,
      WihT, WhhT, Wt1uT, Wt1sT, Wi1uT, Wi1sT, Wa1T);

  k1_gru<<<B_/TB, 256, 0, stream>>>(
      lengths, seq_id_emb, seq_text_emb,
      WihT, WhhT, b_ih, b_hh,
      Wt1uT, bt1, Wi1uT, bi1, Wa1T, ba1, Wa2, ba2,
      u_t, u_i, alp);

  k2_score<<<B_, 256, 0, stream>>>(
      seq_items, lengths, cand_ids,
      cand_id_emb, cand_text_emb, co_table,
      Wt1sT, Wt2, Wi1sT, Wi2,
      u_t, u_i, alp,
      beta_c, logT_c, logT_t, logT_id,
      out);
}